// Round 15
// baseline (809.834 us; speedup 1.0000x reference)
//
#include <hip/hip_runtime.h>
#include <math.h>

// Problem constants (match reference)
#define NU_ 500000
#define NI_ 200000
#define NN_ 700000            // NU + NI
#define D_  64
#define E_  2000000
#define B_  131072
#define TWO_E 4000000

#define SHIFT_ 10             // 1024 nodes per bucket
#define NBUCK_ 684            // ceil(700000 / 1024)
#define BCAP_  12288          // endpoints/bucket cap (item-bucket mean 10240, +20 sigma)
#define B1_TILE 16384         // endpoints per B1 block (256 thr x 64)

typedef _Float16 half4 __attribute__((ext_vector_type(4)));  // 8 B
typedef _Float16 half8 __attribute__((ext_vector_type(8)));  // 16 B

// ---------------------------------------------------------------------------
// B1a: coarse bucket histogram, LDS-aggregated (no random global atomics).
__global__ __launch_bounds__(256) void bucket_hist_kernel(const int* __restrict__ eu,
                                                          const int* __restrict__ ei,
                                                          int* __restrict__ bucketCnt,
                                                          int* __restrict__ rowptr) {
    __shared__ int h[NBUCK_];
    for (int i = threadIdx.x; i < NBUCK_; i += 256) h[i] = 0;
    __syncthreads();
    size_t base = (size_t)blockIdx.x * B1_TILE;
    for (int k = 0; k < 64; ++k) {
        size_t idx = base + (size_t)k * 256 + threadIdx.x;
        if (idx < TWO_E) {
            int e = (int)(idx >> 1);
            int node = (idx & 1) ? (ei[e] + NU_) : eu[e];
            atomicAdd(&h[node >> SHIFT_], 1);
        }
    }
    __syncthreads();
    for (int i = threadIdx.x; i < NBUCK_; i += 256)
        if (h[i]) atomicAdd(&bucketCnt[i], h[i]);
    if (blockIdx.x == 0 && threadIdx.x == 0) rowptr[NN_] = TWO_E;
}

// ---------------------------------------------------------------------------
// Exclusive scan helper (single 1024-elem block, Hillis-Steele in LDS).
__global__ __launch_bounds__(1024) void scan_block(const int* __restrict__ in, int n,
                                                   int* __restrict__ out,
                                                   int* __restrict__ psum) {
    __shared__ int lds[1024];
    int g = blockIdx.x * 1024 + threadIdx.x;
    int v = (g < n) ? in[g] : 0;
    lds[threadIdx.x] = v;
    __syncthreads();
    for (int off = 1; off < 1024; off <<= 1) {
        int t = (threadIdx.x >= (unsigned)off) ? lds[threadIdx.x - off] : 0;
        __syncthreads();
        lds[threadIdx.x] += t;
        __syncthreads();
    }
    if (g < n) out[g] = lds[threadIdx.x] - v;     // exclusive
    if (threadIdx.x == 1023 && psum) psum[blockIdx.x] = lds[1023];
}

// ---------------------------------------------------------------------------
// B1b: scatter (node,nbr) pairs into coarse bucket regions (LDS-ranked).
__global__ __launch_bounds__(256) void bucket_scatter_kernel(const int* __restrict__ eu,
                                                             const int* __restrict__ ei,
                                                             int* __restrict__ cursor,
                                                             unsigned long long* __restrict__ pairs) {
    __shared__ int h[NBUCK_];
    __shared__ int basel[NBUCK_];
    for (int i = threadIdx.x; i < NBUCK_; i += 256) h[i] = 0;
    __syncthreads();
    size_t base = (size_t)blockIdx.x * B1_TILE;
    for (int k = 0; k < 64; ++k) {
        size_t idx = base + (size_t)k * 256 + threadIdx.x;
        if (idx < TWO_E) {
            int e = (int)(idx >> 1);
            int node = (idx & 1) ? (ei[e] + NU_) : eu[e];
            atomicAdd(&h[node >> SHIFT_], 1);
        }
    }
    __syncthreads();
    for (int i = threadIdx.x; i < NBUCK_; i += 256) {
        int c = h[i];
        basel[i] = c ? atomicAdd(&cursor[i], c) : 0;
    }
    __syncthreads();
    for (int i = threadIdx.x; i < NBUCK_; i += 256) h[i] = 0;   // reuse as ranks
    __syncthreads();
    for (int k = 0; k < 64; ++k) {
        size_t idx = base + (size_t)k * 256 + threadIdx.x;
        if (idx < TWO_E) {
            int e = (int)(idx >> 1);
            int side = (int)(idx & 1);
            int u = eu[e];
            int v = ei[e] + NU_;
            int node = side ? v : u;
            int nbr  = side ? u : v;
            int bk = node >> SHIFT_;
            int r = atomicAdd(&h[bk], 1);
            pairs[(size_t)basel[bk] + r] =
                ((unsigned long long)(unsigned)node << 32) | (unsigned)nbr;
        }
    }
}

// ---------------------------------------------------------------------------
// B2: per-bucket CSR build entirely in LDS; all global writes coalesced.
__global__ __launch_bounds__(256) void csr_build_kernel(const unsigned long long* __restrict__ pairs,
                                                        const int* __restrict__ bucketBase,
                                                        int* __restrict__ rowptr,
                                                        int* __restrict__ adj,
                                                        float* __restrict__ inv,
                                                        float* __restrict__ sdeg) {
    __shared__ int cnt[1024];
    __shared__ int sA[1024];
    __shared__ int sB[1024];
    __shared__ int adjl[BCAP_];
    int b  = blockIdx.x;
    int lo = bucketBase[b];
    int hi = (b == NBUCK_ - 1) ? TWO_E : bucketBase[b + 1];
    int sz = hi - lo;
    if (sz > BCAP_) sz = BCAP_;               // defensive (P ~ 0)
    int node0 = b << SHIFT_;
    for (int i = threadIdx.x; i < 1024; i += 256) cnt[i] = 0;
    __syncthreads();
    for (int i = threadIdx.x; i < sz; i += 256) {
        int node = (int)(pairs[(size_t)lo + i] >> 32);
        atomicAdd(&cnt[node & 1023], 1);
    }
    __syncthreads();
    for (int i = threadIdx.x; i < 1024; i += 256) sA[i] = cnt[i];
    __syncthreads();
    int* cur = sA; int* nxt = sB;
    for (int off = 1; off < 1024; off <<= 1) {
        for (int i = threadIdx.x; i < 1024; i += 256)
            nxt[i] = cur[i] + (i >= off ? cur[i - off] : 0);
        __syncthreads();
        int* tmp = cur; cur = nxt; nxt = tmp;
    }
    for (int i = threadIdx.x; i < 1024; i += 256) {
        int excl = cur[i] - cnt[i];
        nxt[i] = excl;
        int node = node0 + i;
        if (node < NN_) {
            rowptr[node] = lo + excl;
            int d = cnt[i];
            inv[node]  = d ? (1.0f / sqrtf((float)d)) : 0.0f;
            sdeg[node] = sqrtf((float)d);
        }
    }
    __syncthreads();
    for (int i = threadIdx.x; i < sz; i += 256) {
        unsigned long long p = pairs[(size_t)lo + i];
        int node = (int)(p >> 32);
        int nbr  = (int)(p & 0xffffffffu);
        int r = atomicAdd(&nxt[node & 1023], 1);
        if (r < BCAP_) adjl[r] = nbr;
    }
    __syncthreads();
    for (int i = threadIdx.x; i < sz; i += 256) adj[lo + i] = adjl[i];
}

// ---------------------------------------------------------------------------
// PRE-SCALED fp16 conversion (runs AFTER the build — needs inv):
// y0[b] = inv[b] * x0[b]. This makes ALL pulls unweighted (y_{l+1} =
// inv^2 * Sum y_l), eliminating the random inv[n] gather from pull-1.
__global__ __launch_bounds__(256) void conv_kernel(const float* __restrict__ ue,
                                                   const float* __restrict__ ie,
                                                   const float* __restrict__ inv,
                                                   half4* __restrict__ xh) {
    int t = blockIdx.x * 256 + threadIdx.x;
    int b = t >> 4;
    int q = t & 15;
    const float4* src = (b < NU_)
        ? ((const float4*)(ue + (size_t)b * D_) + q)
        : ((const float4*)(ie + (size_t)(b - NU_) * D_) + q);
    float4 a = *src;
    float iv = inv[b];
    half4 h;
    h[0] = (_Float16)(iv * a.x); h[1] = (_Float16)(iv * a.y);
    h[2] = (_Float16)(iv * a.z); h[3] = (_Float16)(iv * a.w);
    xh[(size_t)b * 16 + q] = h;
}

// ---------------------------------------------------------------------------
// Unweighted pre-scaled pull (used for BOTH layers):
//   out[v] = fp16( inv[v]^2 * sum_n in[n] )
// lane = g*8+q; masked slots read the dedicated zero row at index NN.
// adj is read exactly once per pull -> non-temporal load; out is written once
// and only re-read next kernel -> non-temporal store (keeps L2 for gathers).
__global__ __launch_bounds__(256) void pull_kernel(const half8* __restrict__ yh,
                                                   const float* __restrict__ inv,
                                                   const int* __restrict__ rowptr,
                                                   const int* __restrict__ adj,
                                                   half8* __restrict__ out) {
    int t = blockIdx.x * 256 + threadIdx.x;
    int v = t >> 6;
    int lane = t & 63;
    int g = lane >> 3;        // neighbor slot (0..7)
    int q = lane & 7;         // feature octet
    int beg = rowptr[v];
    int end = rowptr[v + 1];
    float acc[8] = {0.f, 0.f, 0.f, 0.f, 0.f, 0.f, 0.f, 0.f};
    for (int j = beg; j < end; j += 8) {
        int i = j + g;
        int n = __builtin_nontemporal_load(&adj[i]);  // over-read stays in-ws
        n = (i < end) ? n : NN_;                      // masked -> zero row
        half8 a = yh[(size_t)n * 8 + q];
#pragma unroll
        for (int k = 0; k < 8; ++k)
            acc[k] += (float)a[k];
    }
#pragma unroll
    for (int k = 0; k < 8; ++k) {
        acc[k] += __shfl_xor(acc[k], 8);
        acc[k] += __shfl_xor(acc[k], 16);
        acc[k] += __shfl_xor(acc[k], 32);
    }
    if (g == 0) {
        float iv = inv[v];
        float iv2 = iv * iv;
        half8 o;
#pragma unroll
        for (int k = 0; k < 8; ++k) o[k] = (_Float16)(iv2 * acc[k]);
        __builtin_nontemporal_store(o, &out[(size_t)v * 8 + q]);
    }
}

// ---------------------------------------------------------------------------
// Per-node finalization with pre-scaled layers:
//   Zfinal[lane] = emb + (y1+y2)*sdeg[node] + inv[node]*sum_n y2[n]
__device__ __forceinline__ float node_final(int node,
                                            const float* __restrict__ embrow,
                                            const _Float16* __restrict__ y1,
                                            const _Float16* __restrict__ y2,
                                            const float* __restrict__ inv,
                                            const float* __restrict__ sdeg,
                                            const int* __restrict__ rowptr,
                                            const int* __restrict__ adj,
                                            int lane, int g, int q) {
    int beg = rowptr[node];
    int end = rowptr[node + 1];
    float acc[8] = {0.f, 0.f, 0.f, 0.f, 0.f, 0.f, 0.f, 0.f};
    for (int j = beg; j < end; j += 8) {
        int i = j + g;
        int n = adj[i];
        n = (i < end) ? n : NN_;          // masked -> zero row
        half8 a = *(const half8*)(y2 + ((unsigned)n * 64u + (unsigned)q * 8u));
#pragma unroll
        for (int k = 0; k < 8; ++k)
            acc[k] += (float)a[k];
    }
#pragma unroll
    for (int k = 0; k < 8; ++k) {
        acc[k] += __shfl_xor(acc[k], 8);
        acc[k] += __shfl_xor(acc[k], 16);
        acc[k] += __shfl_xor(acc[k], 32);
    }
    float red = 0.0f;
#pragma unroll
    for (int k = 0; k < 8; ++k) {
        float tmp = __shfl(acc[k], lane >> 3);
        red = ((lane & 7) == k) ? tmp : red;
    }
    float s   = sdeg[node];
    float l12 = ((float)y1[(unsigned)node * 64u + (unsigned)lane]
               + (float)y2[(unsigned)node * 64u + (unsigned)lane]) * s;
    return embrow[lane] + l12 + inv[node] * red;
}

// ---------------------------------------------------------------------------
// Fully fused finalize + score: one wave per pair b.
__global__ __launch_bounds__(256) void final_score_kernel(
        const float* __restrict__ ue,
        const float* __restrict__ ie,
        const _Float16* __restrict__ y1,
        const _Float16* __restrict__ y2,
        const float* __restrict__ inv,
        const float* __restrict__ sdeg,
        const int* __restrict__ rowptr,
        const int* __restrict__ adj,
        const int* __restrict__ users,
        const int* __restrict__ items,
        const float* __restrict__ fw,
        float* __restrict__ out) {
    int t = blockIdx.x * 256 + threadIdx.x;
    int b = t >> 6;
    int lane = t & 63;
    int g = lane >> 3;
    int q = lane & 7;

    int u  = users[b];
    int io = items[b];
    int it = io + NU_;
    float zu = node_final(u,  ue + (size_t)u * D_,  y1, y2, inv, sdeg, rowptr, adj, lane, g, q);
    float zi = node_final(it, ie + (size_t)io * D_, y1, y2, inv, sdeg, rowptr, adj, lane, g, q);

    int f = lane >> 4;
    float s = 0.0f;
#pragma unroll
    for (int gg = 0; gg < 4; ++gg) {
        float pi = __shfl(zi, (gg << 4) | (lane & 15));
        float p = zu * pi;
        p += __shfl_xor(p, 1);
        p += __shfl_xor(p, 2);
        p += __shfl_xor(p, 4);
        p += __shfl_xor(p, 8);
        s += fw[f * 4 + gg] * p;
    }
    s += __shfl_xor(s, 16);
    s += __shfl_xor(s, 32);
    if (lane == 0) out[b] = s * 0.0625f;  // (1/4)*(1/4) layer-mean scaling
}

// ---------------------------------------------------------------------------
extern "C" void kernel_launch(void* const* d_in, const int* in_sizes, int n_in,
                              void* d_out, int out_size, void* d_ws, size_t ws_size,
                              hipStream_t stream) {
    const float* ue    = (const float*)d_in[0];  // [NU, 64]
    const float* ie    = (const float*)d_in[1];  // [NI, 64]
    const float* fw    = (const float*)d_in[2];  // [4, 4]
    const int*   eu    = (const int*)d_in[3];    // [E]
    const int*   eitem = (const int*)d_in[4];    // [E]
    const int*   users = (const int*)d_in[5];    // [B]
    const int*   items = (const int*)d_in[6];    // [B]
    float* scores = (float*)d_out;               // [B]

    // (NN+1) rows: row NN is the dedicated zero row for masked gathers.
    const size_t xh_bytes = (size_t)(NN_ + 1) * D_ * 2;       // 89.6 MB + 128 B

    char* ws = (char*)d_ws;
    half8* X0h  = (half8*)ws;  ws += xh_bytes;    // y0 = inv*x0; reused as y2 out
    half8* XAh  = (half8*)ws;  ws += xh_bytes;    // y1
    unsigned long long* pairs = (unsigned long long*)ws; ws += (size_t)TWO_E * 8;  // 32 MB
    int*   adj  = (int*)ws;    ws += (size_t)TWO_E * 4;       // 16 MB
    int*   rowptr = (int*)ws;  ws += (size_t)(NN_ + 1) * 4;
    float* inv  = (float*)ws;  ws += (size_t)NN_ * 4;
    float* sdeg = (float*)ws;  ws += (size_t)NN_ * 4;
    int*   bucketCnt  = (int*)ws; ws += (size_t)NBUCK_ * 4;
    int*   bucketBase = (int*)ws; ws += (size_t)NBUCK_ * 4;
    int*   cursor     = (int*)ws; ws += (size_t)NBUCK_ * 4;
    half8* XBh  = X0h;          // ping-pong: X0h dead after pull-1

    // --- bucket-sort CSR build ------------------------------------------
    hipMemsetAsync(bucketCnt, 0, (size_t)NBUCK_ * 4, stream);
    hipMemsetAsync((char*)X0h + (size_t)NN_ * 128, 0, 128, stream);
    hipMemsetAsync((char*)XAh + (size_t)NN_ * 128, 0, 128, stream);
    const int NB1 = (TWO_E + B1_TILE - 1) / B1_TILE;          // 245
    bucket_hist_kernel<<<NB1, 256, 0, stream>>>(eu, eitem, bucketCnt, rowptr);
    scan_block<<<1, 1024, 0, stream>>>(bucketCnt, NBUCK_, bucketBase, (int*)nullptr);
    hipMemcpyAsync(cursor, bucketBase, (size_t)NBUCK_ * 4, hipMemcpyDeviceToDevice, stream);
    bucket_scatter_kernel<<<NB1, 256, 0, stream>>>(eu, eitem, cursor, pairs);
    csr_build_kernel<<<NBUCK_, 256, 0, stream>>>(pairs, bucketBase, rowptr, adj, inv, sdeg);

    // --- pre-scaled fp16 conversion (after build: needs inv) ------------
    conv_kernel<<<(NN_ * 16) / 256, 256, 0, stream>>>(ue, ie, inv, (half4*)X0h);

    // --- propagation: y1 = inv^2*Sum y0; y2 = inv^2*Sum y1 (unweighted) -
    pull_kernel<<<(NN_ * D_) / 256, 256, 0, stream>>>(X0h, inv, rowptr, adj, XAh);
    pull_kernel<<<(NN_ * D_) / 256, 256, 0, stream>>>(XAh, inv, rowptr, adj, XBh);

    // --- fused finalize (emb + (y1+y2)*sdeg + inv*Sum y2) + score -------
    final_score_kernel<<<(B_ * D_) / 256, 256, 0, stream>>>(
        ue, ie, (const _Float16*)XAh, (const _Float16*)XBh,
        inv, sdeg, rowptr, adj, users, items, fw, scores);
}

// Round 16
// 749.286 us; speedup vs baseline: 1.0808x; 1.0808x over previous
//
#include <hip/hip_runtime.h>
#include <math.h>

// Problem constants (match reference)
#define NU_ 500000
#define NI_ 200000
#define NN_ 700000            // NU + NI
#define D_  64
#define E_  2000000
#define B_  131072
#define TWO_E 4000000

#define SHIFT_ 10             // 1024 nodes per bucket
#define NBUCK_ 684            // ceil(700000 / 1024)
#define BCAP_  12288          // endpoints/bucket cap (item-bucket mean 10240, +20 sigma)
#define B1_TILE 16384         // endpoints per B1 block (256 thr x 64)

typedef _Float16 half4 __attribute__((ext_vector_type(4)));  // 8 B
typedef _Float16 half8 __attribute__((ext_vector_type(8)));  // 16 B

// ---------------------------------------------------------------------------
// B1a: coarse bucket histogram, LDS-aggregated (no random global atomics).
__global__ __launch_bounds__(256) void bucket_hist_kernel(const int* __restrict__ eu,
                                                          const int* __restrict__ ei,
                                                          int* __restrict__ bucketCnt,
                                                          int* __restrict__ rowptr) {
    __shared__ int h[NBUCK_];
    for (int i = threadIdx.x; i < NBUCK_; i += 256) h[i] = 0;
    __syncthreads();
    size_t base = (size_t)blockIdx.x * B1_TILE;
    for (int k = 0; k < 64; ++k) {
        size_t idx = base + (size_t)k * 256 + threadIdx.x;
        if (idx < TWO_E) {
            int e = (int)(idx >> 1);
            int node = (idx & 1) ? (ei[e] + NU_) : eu[e];
            atomicAdd(&h[node >> SHIFT_], 1);
        }
    }
    __syncthreads();
    for (int i = threadIdx.x; i < NBUCK_; i += 256)
        if (h[i]) atomicAdd(&bucketCnt[i], h[i]);
    if (blockIdx.x == 0 && threadIdx.x == 0) rowptr[NN_] = TWO_E;
}

// ---------------------------------------------------------------------------
// Exclusive scan helper (single 1024-elem block, Hillis-Steele in LDS).
__global__ __launch_bounds__(1024) void scan_block(const int* __restrict__ in, int n,
                                                   int* __restrict__ out,
                                                   int* __restrict__ psum) {
    __shared__ int lds[1024];
    int g = blockIdx.x * 1024 + threadIdx.x;
    int v = (g < n) ? in[g] : 0;
    lds[threadIdx.x] = v;
    __syncthreads();
    for (int off = 1; off < 1024; off <<= 1) {
        int t = (threadIdx.x >= (unsigned)off) ? lds[threadIdx.x - off] : 0;
        __syncthreads();
        lds[threadIdx.x] += t;
        __syncthreads();
    }
    if (g < n) out[g] = lds[threadIdx.x] - v;     // exclusive
    if (threadIdx.x == 1023 && psum) psum[blockIdx.x] = lds[1023];
}

// ---------------------------------------------------------------------------
// B1b: scatter (node,nbr) pairs into coarse bucket regions (LDS-ranked).
__global__ __launch_bounds__(256) void bucket_scatter_kernel(const int* __restrict__ eu,
                                                             const int* __restrict__ ei,
                                                             int* __restrict__ cursor,
                                                             unsigned long long* __restrict__ pairs) {
    __shared__ int h[NBUCK_];
    __shared__ int basel[NBUCK_];
    for (int i = threadIdx.x; i < NBUCK_; i += 256) h[i] = 0;
    __syncthreads();
    size_t base = (size_t)blockIdx.x * B1_TILE;
    for (int k = 0; k < 64; ++k) {
        size_t idx = base + (size_t)k * 256 + threadIdx.x;
        if (idx < TWO_E) {
            int e = (int)(idx >> 1);
            int node = (idx & 1) ? (ei[e] + NU_) : eu[e];
            atomicAdd(&h[node >> SHIFT_], 1);
        }
    }
    __syncthreads();
    for (int i = threadIdx.x; i < NBUCK_; i += 256) {
        int c = h[i];
        basel[i] = c ? atomicAdd(&cursor[i], c) : 0;
    }
    __syncthreads();
    for (int i = threadIdx.x; i < NBUCK_; i += 256) h[i] = 0;   // reuse as ranks
    __syncthreads();
    for (int k = 0; k < 64; ++k) {
        size_t idx = base + (size_t)k * 256 + threadIdx.x;
        if (idx < TWO_E) {
            int e = (int)(idx >> 1);
            int side = (int)(idx & 1);
            int u = eu[e];
            int v = ei[e] + NU_;
            int node = side ? v : u;
            int nbr  = side ? u : v;
            int bk = node >> SHIFT_;
            int r = atomicAdd(&h[bk], 1);
            pairs[(size_t)basel[bk] + r] =
                ((unsigned long long)(unsigned)node << 32) | (unsigned)nbr;
        }
    }
}

// ---------------------------------------------------------------------------
// B2: per-bucket CSR build entirely in LDS; all global writes coalesced.
__global__ __launch_bounds__(256) void csr_build_kernel(const unsigned long long* __restrict__ pairs,
                                                        const int* __restrict__ bucketBase,
                                                        int* __restrict__ rowptr,
                                                        int* __restrict__ adj,
                                                        float* __restrict__ inv,
                                                        float* __restrict__ sdeg) {
    __shared__ int cnt[1024];
    __shared__ int sA[1024];
    __shared__ int sB[1024];
    __shared__ int adjl[BCAP_];
    int b  = blockIdx.x;
    int lo = bucketBase[b];
    int hi = (b == NBUCK_ - 1) ? TWO_E : bucketBase[b + 1];
    int sz = hi - lo;
    if (sz > BCAP_) sz = BCAP_;               // defensive (P ~ 0)
    int node0 = b << SHIFT_;
    for (int i = threadIdx.x; i < 1024; i += 256) cnt[i] = 0;
    __syncthreads();
    for (int i = threadIdx.x; i < sz; i += 256) {
        int node = (int)(pairs[(size_t)lo + i] >> 32);
        atomicAdd(&cnt[node & 1023], 1);
    }
    __syncthreads();
    for (int i = threadIdx.x; i < 1024; i += 256) sA[i] = cnt[i];
    __syncthreads();
    int* cur = sA; int* nxt = sB;
    for (int off = 1; off < 1024; off <<= 1) {
        for (int i = threadIdx.x; i < 1024; i += 256)
            nxt[i] = cur[i] + (i >= off ? cur[i - off] : 0);
        __syncthreads();
        int* tmp = cur; cur = nxt; nxt = tmp;
    }
    for (int i = threadIdx.x; i < 1024; i += 256) {
        int excl = cur[i] - cnt[i];
        nxt[i] = excl;
        int node = node0 + i;
        if (node < NN_) {
            rowptr[node] = lo + excl;
            int d = cnt[i];
            inv[node]  = d ? (1.0f / sqrtf((float)d)) : 0.0f;
            sdeg[node] = sqrtf((float)d);
        }
    }
    __syncthreads();
    for (int i = threadIdx.x; i < sz; i += 256) {
        unsigned long long p = pairs[(size_t)lo + i];
        int node = (int)(p >> 32);
        int nbr  = (int)(p & 0xffffffffu);
        int r = atomicAdd(&nxt[node & 1023], 1);
        if (r < BCAP_) adjl[r] = nbr;
    }
    __syncthreads();
    for (int i = threadIdx.x; i < sz; i += 256) adj[lo + i] = adjl[i];
}

// ---------------------------------------------------------------------------
// PRE-SCALED fp16 conversion (runs AFTER the build — needs inv):
// y0[b] = inv[b] * x0[b]. Makes ALL pulls unweighted (y_{l+1} = inv^2*Sum y_l).
__global__ __launch_bounds__(256) void conv_kernel(const float* __restrict__ ue,
                                                   const float* __restrict__ ie,
                                                   const float* __restrict__ inv,
                                                   half4* __restrict__ xh) {
    int t = blockIdx.x * 256 + threadIdx.x;
    int b = t >> 4;
    int q = t & 15;
    const float4* src = (b < NU_)
        ? ((const float4*)(ue + (size_t)b * D_) + q)
        : ((const float4*)(ie + (size_t)(b - NU_) * D_) + q);
    float4 a = *src;
    float iv = inv[b];
    half4 h;
    h[0] = (_Float16)(iv * a.x); h[1] = (_Float16)(iv * a.y);
    h[2] = (_Float16)(iv * a.z); h[3] = (_Float16)(iv * a.w);
    xh[(size_t)b * 16 + q] = h;
}

// ---------------------------------------------------------------------------
// Unweighted pre-scaled pull (used for BOTH layers), PLAIN loads/stores
// (R15 A/B: NT store evicted y from L2 and slowed the downstream consumers;
// NT load killed cross-wave adj line reuse — net +55 µs, reverted):
//   out[v] = fp16( inv[v]^2 * sum_n in[n] )
__global__ __launch_bounds__(256) void pull_kernel(const half8* __restrict__ yh,
                                                   const float* __restrict__ inv,
                                                   const int* __restrict__ rowptr,
                                                   const int* __restrict__ adj,
                                                   half8* __restrict__ out) {
    int t = blockIdx.x * 256 + threadIdx.x;
    int v = t >> 6;
    int lane = t & 63;
    int g = lane >> 3;        // neighbor slot (0..7)
    int q = lane & 7;         // feature octet
    int beg = rowptr[v];
    int end = rowptr[v + 1];
    float acc[8] = {0.f, 0.f, 0.f, 0.f, 0.f, 0.f, 0.f, 0.f};
    for (int j = beg; j < end; j += 8) {
        int i = j + g;
        int n = adj[i];                   // over-read (<8) lands in rowptr: safe
        n = (i < end) ? n : NN_;          // masked -> zero row
        half8 a = yh[(size_t)n * 8 + q];
#pragma unroll
        for (int k = 0; k < 8; ++k)
            acc[k] += (float)a[k];
    }
#pragma unroll
    for (int k = 0; k < 8; ++k) {
        acc[k] += __shfl_xor(acc[k], 8);
        acc[k] += __shfl_xor(acc[k], 16);
        acc[k] += __shfl_xor(acc[k], 32);
    }
    if (g == 0) {
        float iv = inv[v];
        float iv2 = iv * iv;
        half8 o;
#pragma unroll
        for (int k = 0; k < 8; ++k) o[k] = (_Float16)(iv2 * acc[k]);
        out[(size_t)v * 8 + q] = o;
    }
}

// ---------------------------------------------------------------------------
// Per-node finalization with pre-scaled layers:
//   Zfinal[lane] = emb + (y1+y2)*sdeg[node] + inv[node]*sum_n y2[n]
__device__ __forceinline__ float node_final(int node,
                                            const float* __restrict__ embrow,
                                            const _Float16* __restrict__ y1,
                                            const _Float16* __restrict__ y2,
                                            const float* __restrict__ inv,
                                            const float* __restrict__ sdeg,
                                            const int* __restrict__ rowptr,
                                            const int* __restrict__ adj,
                                            int lane, int g, int q) {
    int beg = rowptr[node];
    int end = rowptr[node + 1];
    float acc[8] = {0.f, 0.f, 0.f, 0.f, 0.f, 0.f, 0.f, 0.f};
    for (int j = beg; j < end; j += 8) {
        int i = j + g;
        int n = adj[i];
        n = (i < end) ? n : NN_;          // masked -> zero row
        half8 a = *(const half8*)(y2 + ((unsigned)n * 64u + (unsigned)q * 8u));
#pragma unroll
        for (int k = 0; k < 8; ++k)
            acc[k] += (float)a[k];
    }
#pragma unroll
    for (int k = 0; k < 8; ++k) {
        acc[k] += __shfl_xor(acc[k], 8);
        acc[k] += __shfl_xor(acc[k], 16);
        acc[k] += __shfl_xor(acc[k], 32);
    }
    float red = 0.0f;
#pragma unroll
    for (int k = 0; k < 8; ++k) {
        float tmp = __shfl(acc[k], lane >> 3);
        red = ((lane & 7) == k) ? tmp : red;
    }
    float s   = sdeg[node];
    float l12 = ((float)y1[(unsigned)node * 64u + (unsigned)lane]
               + (float)y2[(unsigned)node * 64u + (unsigned)lane]) * s;
    return embrow[lane] + l12 + inv[node] * red;
}

// ---------------------------------------------------------------------------
// Fully fused finalize + score: one wave per pair b.
__global__ __launch_bounds__(256) void final_score_kernel(
        const float* __restrict__ ue,
        const float* __restrict__ ie,
        const _Float16* __restrict__ y1,
        const _Float16* __restrict__ y2,
        const float* __restrict__ inv,
        const float* __restrict__ sdeg,
        const int* __restrict__ rowptr,
        const int* __restrict__ adj,
        const int* __restrict__ users,
        const int* __restrict__ items,
        const float* __restrict__ fw,
        float* __restrict__ out) {
    int t = blockIdx.x * 256 + threadIdx.x;
    int b = t >> 6;
    int lane = t & 63;
    int g = lane >> 3;
    int q = lane & 7;

    int u  = users[b];
    int io = items[b];
    int it = io + NU_;
    float zu = node_final(u,  ue + (size_t)u * D_,  y1, y2, inv, sdeg, rowptr, adj, lane, g, q);
    float zi = node_final(it, ie + (size_t)io * D_, y1, y2, inv, sdeg, rowptr, adj, lane, g, q);

    int f = lane >> 4;
    float s = 0.0f;
#pragma unroll
    for (int gg = 0; gg < 4; ++gg) {
        float pi = __shfl(zi, (gg << 4) | (lane & 15));
        float p = zu * pi;
        p += __shfl_xor(p, 1);
        p += __shfl_xor(p, 2);
        p += __shfl_xor(p, 4);
        p += __shfl_xor(p, 8);
        s += fw[f * 4 + gg] * p;
    }
    s += __shfl_xor(s, 16);
    s += __shfl_xor(s, 32);
    if (lane == 0) out[b] = s * 0.0625f;  // (1/4)*(1/4) layer-mean scaling
}

// ---------------------------------------------------------------------------
extern "C" void kernel_launch(void* const* d_in, const int* in_sizes, int n_in,
                              void* d_out, int out_size, void* d_ws, size_t ws_size,
                              hipStream_t stream) {
    const float* ue    = (const float*)d_in[0];  // [NU, 64]
    const float* ie    = (const float*)d_in[1];  // [NI, 64]
    const float* fw    = (const float*)d_in[2];  // [4, 4]
    const int*   eu    = (const int*)d_in[3];    // [E]
    const int*   eitem = (const int*)d_in[4];    // [E]
    const int*   users = (const int*)d_in[5];    // [B]
    const int*   items = (const int*)d_in[6];    // [B]
    float* scores = (float*)d_out;               // [B]

    // (NN+1) rows: row NN is the dedicated zero row for masked gathers.
    const size_t xh_bytes = (size_t)(NN_ + 1) * D_ * 2;       // 89.6 MB + 128 B

    char* ws = (char*)d_ws;
    half8* X0h  = (half8*)ws;  ws += xh_bytes;    // y0 = inv*x0; reused as y2 out
    half8* XAh  = (half8*)ws;  ws += xh_bytes;    // y1
    unsigned long long* pairs = (unsigned long long*)ws; ws += (size_t)TWO_E * 8;  // 32 MB
    int*   adj  = (int*)ws;    ws += (size_t)TWO_E * 4;       // 16 MB
    int*   rowptr = (int*)ws;  ws += (size_t)(NN_ + 1) * 4;
    float* inv  = (float*)ws;  ws += (size_t)NN_ * 4;
    float* sdeg = (float*)ws;  ws += (size_t)NN_ * 4;
    int*   bucketCnt  = (int*)ws; ws += (size_t)NBUCK_ * 4;
    int*   bucketBase = (int*)ws; ws += (size_t)NBUCK_ * 4;
    int*   cursor     = (int*)ws; ws += (size_t)NBUCK_ * 4;
    half8* XBh  = X0h;          // ping-pong: X0h dead after pull-1

    // --- bucket-sort CSR build ------------------------------------------
    hipMemsetAsync(bucketCnt, 0, (size_t)NBUCK_ * 4, stream);
    hipMemsetAsync((char*)X0h + (size_t)NN_ * 128, 0, 128, stream);
    hipMemsetAsync((char*)XAh + (size_t)NN_ * 128, 0, 128, stream);
    const int NB1 = (TWO_E + B1_TILE - 1) / B1_TILE;          // 245
    bucket_hist_kernel<<<NB1, 256, 0, stream>>>(eu, eitem, bucketCnt, rowptr);
    scan_block<<<1, 1024, 0, stream>>>(bucketCnt, NBUCK_, bucketBase, (int*)nullptr);
    hipMemcpyAsync(cursor, bucketBase, (size_t)NBUCK_ * 4, hipMemcpyDeviceToDevice, stream);
    bucket_scatter_kernel<<<NB1, 256, 0, stream>>>(eu, eitem, cursor, pairs);
    csr_build_kernel<<<NBUCK_, 256, 0, stream>>>(pairs, bucketBase, rowptr, adj, inv, sdeg);

    // --- pre-scaled fp16 conversion (after build: needs inv) ------------
    conv_kernel<<<(NN_ * 16) / 256, 256, 0, stream>>>(ue, ie, inv, (half4*)X0h);

    // --- propagation: y1 = inv^2*Sum y0; y2 = inv^2*Sum y1 (unweighted) -
    pull_kernel<<<(NN_ * D_) / 256, 256, 0, stream>>>(X0h, inv, rowptr, adj, XAh);
    pull_kernel<<<(NN_ * D_) / 256, 256, 0, stream>>>(XAh, inv, rowptr, adj, XBh);

    // --- fused finalize (emb + (y1+y2)*sdeg + inv*Sum y2) + score -------
    final_score_kernel<<<(B_ * D_) / 256, 256, 0, stream>>>(
        ue, ie, (const _Float16*)XAh, (const _Float16*)XBh,
        inv, sdeg, rowptr, adj, users, items, fw, scores);
}

// Round 17
// 716.829 us; speedup vs baseline: 1.1297x; 1.0453x over previous
//
#include <hip/hip_runtime.h>
#include <math.h>

// Problem constants (match reference)
#define NU_ 500000
#define NI_ 200000
#define NN_ 700000            // NU + NI
#define D_  64
#define E_  2000000
#define B_  131072
#define TWO_E 4000000

#define SHIFT_ 10             // 1024 nodes per bucket
#define NBUCK_ 684            // ceil(700000 / 1024)
#define BCAP_  12288          // endpoints/bucket cap (item-bucket mean 10240, +20 sigma)
#define B1_TILE 16384         // endpoints per B1 block (256 thr x 64)
#define NB1_   245            // ceil(2E / B1_TILE)
#define NTOT_  (NBUCK_ * NB1_)   // 167,580 block-bucket cells
#define NSCAN2_ ((NTOT_ + 1023) / 1024)  // 164

typedef _Float16 half4 __attribute__((ext_vector_type(4)));  // 8 B
typedef _Float16 half8 __attribute__((ext_vector_type(8)));  // 16 B

// ---------------------------------------------------------------------------
// B1a: per-block bucket histogram -> blockHist[bk*NB1 + blk] (bucket-major).
// No global atomics at all; the scan of blockHist gives every scatter block
// its exact, deterministic write base per bucket.
__global__ __launch_bounds__(256) void bucket_hist_kernel(const int* __restrict__ eu,
                                                          const int* __restrict__ ei,
                                                          int* __restrict__ blockHist,
                                                          int* __restrict__ rowptr) {
    __shared__ int h[NBUCK_];
    for (int i = threadIdx.x; i < NBUCK_; i += 256) h[i] = 0;
    __syncthreads();
    size_t base = (size_t)blockIdx.x * B1_TILE;
    for (int k = 0; k < 64; ++k) {
        size_t idx = base + (size_t)k * 256 + threadIdx.x;
        if (idx < TWO_E) {
            int e = (int)(idx >> 1);
            int node = (idx & 1) ? (ei[e] + NU_) : eu[e];
            atomicAdd(&h[node >> SHIFT_], 1);
        }
    }
    __syncthreads();
    for (int i = threadIdx.x; i < NBUCK_; i += 256)
        blockHist[(size_t)i * NB1_ + blockIdx.x] = h[i];
    if (blockIdx.x == 0 && threadIdx.x == 0) rowptr[NN_] = TWO_E;
}

// ---------------------------------------------------------------------------
// Exclusive scan (1024-elem blocks, Hillis-Steele in LDS) + add helper.
__global__ __launch_bounds__(1024) void scan_block(const int* __restrict__ in, int n,
                                                   int* __restrict__ out,
                                                   int* __restrict__ psum) {
    __shared__ int lds[1024];
    int g = blockIdx.x * 1024 + threadIdx.x;
    int v = (g < n) ? in[g] : 0;
    lds[threadIdx.x] = v;
    __syncthreads();
    for (int off = 1; off < 1024; off <<= 1) {
        int t = (threadIdx.x >= (unsigned)off) ? lds[threadIdx.x - off] : 0;
        __syncthreads();
        lds[threadIdx.x] += t;
        __syncthreads();
    }
    if (g < n) out[g] = lds[threadIdx.x] - v;     // exclusive
    if (threadIdx.x == 1023 && psum) psum[blockIdx.x] = lds[1023];
}

__global__ __launch_bounds__(256) void scan_add_kernel(int* __restrict__ a,
                                                       const int* __restrict__ poff,
                                                       int n) {
    int g = blockIdx.x * 256 + threadIdx.x;
    if (g < n) a[g] += poff[g >> 10];
}

// ---------------------------------------------------------------------------
// B1b: scatter packed (local10|nbr20) pairs into bucket regions. Single edge
// pass: write bases come from the scanned blockHist (basel), ranks from LDS.
__global__ __launch_bounds__(256) void bucket_scatter_kernel(const int* __restrict__ eu,
                                                             const int* __restrict__ ei,
                                                             const int* __restrict__ bhScan,
                                                             unsigned int* __restrict__ pairs) {
    __shared__ int h[NBUCK_];      // ranks within this block's bucket segment
    __shared__ int basel[NBUCK_];
    for (int i = threadIdx.x; i < NBUCK_; i += 256) {
        h[i] = 0;
        basel[i] = bhScan[(size_t)i * NB1_ + blockIdx.x];
    }
    __syncthreads();
    size_t base = (size_t)blockIdx.x * B1_TILE;
    for (int k = 0; k < 64; ++k) {
        size_t idx = base + (size_t)k * 256 + threadIdx.x;
        if (idx < TWO_E) {
            int e = (int)(idx >> 1);
            int side = (int)(idx & 1);
            int u = eu[e];
            int v = ei[e] + NU_;
            int node = side ? v : u;
            int nbr  = side ? u : v;
            int bk = node >> SHIFT_;
            int r = atomicAdd(&h[bk], 1);
            pairs[(size_t)basel[bk] + r] =
                ((unsigned)(node & 1023) << 20) | (unsigned)nbr;
        }
    }
}

// ---------------------------------------------------------------------------
// B2: per-bucket CSR build entirely in LDS; all global writes coalesced.
__global__ __launch_bounds__(256) void csr_build_kernel(const unsigned int* __restrict__ pairs,
                                                        const int* __restrict__ bhScan,
                                                        int* __restrict__ rowptr,
                                                        int* __restrict__ adj,
                                                        float* __restrict__ inv,
                                                        float* __restrict__ sdeg) {
    __shared__ int cnt[1024];
    __shared__ int sA[1024];
    __shared__ int sB[1024];
    __shared__ int adjl[BCAP_];
    int b  = blockIdx.x;
    int lo = bhScan[(size_t)b * NB1_];
    int hi = (b == NBUCK_ - 1) ? TWO_E : bhScan[(size_t)(b + 1) * NB1_];
    int sz = hi - lo;
    if (sz > BCAP_) sz = BCAP_;               // defensive (P ~ 0)
    int node0 = b << SHIFT_;
    for (int i = threadIdx.x; i < 1024; i += 256) cnt[i] = 0;
    __syncthreads();
    for (int i = threadIdx.x; i < sz; i += 256) {
        atomicAdd(&cnt[pairs[(size_t)lo + i] >> 20], 1);
    }
    __syncthreads();
    for (int i = threadIdx.x; i < 1024; i += 256) sA[i] = cnt[i];
    __syncthreads();
    int* cur = sA; int* nxt = sB;
    for (int off = 1; off < 1024; off <<= 1) {
        for (int i = threadIdx.x; i < 1024; i += 256)
            nxt[i] = cur[i] + (i >= off ? cur[i - off] : 0);
        __syncthreads();
        int* tmp = cur; cur = nxt; nxt = tmp;
    }
    for (int i = threadIdx.x; i < 1024; i += 256) {
        int excl = cur[i] - cnt[i];
        nxt[i] = excl;
        int node = node0 + i;
        if (node < NN_) {
            rowptr[node] = lo + excl;
            int d = cnt[i];
            inv[node]  = d ? (1.0f / sqrtf((float)d)) : 0.0f;
            sdeg[node] = sqrtf((float)d);
        }
    }
    __syncthreads();
    for (int i = threadIdx.x; i < sz; i += 256) {
        unsigned int p = pairs[(size_t)lo + i];
        int r = atomicAdd(&nxt[p >> 20], 1);
        if (r < BCAP_) adjl[r] = (int)(p & 0xFFFFFu);
    }
    __syncthreads();
    for (int i = threadIdx.x; i < sz; i += 256) adj[lo + i] = adjl[i];
}

// ---------------------------------------------------------------------------
// PRE-SCALED fp16 conversion (after build — needs inv): y0 = inv * x0.
__global__ __launch_bounds__(256) void conv_kernel(const float* __restrict__ ue,
                                                   const float* __restrict__ ie,
                                                   const float* __restrict__ inv,
                                                   half4* __restrict__ xh) {
    int t = blockIdx.x * 256 + threadIdx.x;
    int b = t >> 4;
    int q = t & 15;
    const float4* src = (b < NU_)
        ? ((const float4*)(ue + (size_t)b * D_) + q)
        : ((const float4*)(ie + (size_t)(b - NU_) * D_) + q);
    float4 a = *src;
    float iv = inv[b];
    half4 h;
    h[0] = (_Float16)(iv * a.x); h[1] = (_Float16)(iv * a.y);
    h[2] = (_Float16)(iv * a.z); h[3] = (_Float16)(iv * a.w);
    xh[(size_t)b * 16 + q] = h;
}

// ---------------------------------------------------------------------------
// Unweighted pre-scaled pull (both layers), plain loads/stores (R15 lesson):
//   out[v] = fp16( inv[v]^2 * sum_n in[n] )
__global__ __launch_bounds__(256) void pull_kernel(const half8* __restrict__ yh,
                                                   const float* __restrict__ inv,
                                                   const int* __restrict__ rowptr,
                                                   const int* __restrict__ adj,
                                                   half8* __restrict__ out) {
    int t = blockIdx.x * 256 + threadIdx.x;
    int v = t >> 6;
    int lane = t & 63;
    int g = lane >> 3;        // neighbor slot (0..7)
    int q = lane & 7;         // feature octet
    int beg = rowptr[v];
    int end = rowptr[v + 1];
    float acc[8] = {0.f, 0.f, 0.f, 0.f, 0.f, 0.f, 0.f, 0.f};
    for (int j = beg; j < end; j += 8) {
        int i = j + g;
        int n = adj[i];                   // over-read (<8) lands in rowptr: safe
        n = (i < end) ? n : NN_;          // masked -> zero row
        half8 a = yh[(size_t)n * 8 + q];
#pragma unroll
        for (int k = 0; k < 8; ++k)
            acc[k] += (float)a[k];
    }
#pragma unroll
    for (int k = 0; k < 8; ++k) {
        acc[k] += __shfl_xor(acc[k], 8);
        acc[k] += __shfl_xor(acc[k], 16);
        acc[k] += __shfl_xor(acc[k], 32);
    }
    if (g == 0) {
        float iv = inv[v];
        float iv2 = iv * iv;
        half8 o;
#pragma unroll
        for (int k = 0; k < 8; ++k) o[k] = (_Float16)(iv2 * acc[k]);
        out[(size_t)v * 8 + q] = o;
    }
}

// ---------------------------------------------------------------------------
// Fully fused finalize + score, MERGED dual layer-3 pull: the user and item
// neighbor loops run in ONE loop (16 rows in flight/wave instead of 8),
// halving the exposed gather latency of this kernel.
__global__ __launch_bounds__(256) void final_score_kernel(
        const float* __restrict__ ue,
        const float* __restrict__ ie,
        const _Float16* __restrict__ y1,
        const _Float16* __restrict__ y2,
        const float* __restrict__ inv,
        const float* __restrict__ sdeg,
        const int* __restrict__ rowptr,
        const int* __restrict__ adj,
        const int* __restrict__ users,
        const int* __restrict__ items,
        const float* __restrict__ fw,
        float* __restrict__ out) {
    int t = blockIdx.x * 256 + threadIdx.x;
    int b = t >> 6;
    int lane = t & 63;
    int g = lane >> 3;
    int q = lane & 7;

    int u  = users[b];
    int io = items[b];
    int it = io + NU_;
    int begU = rowptr[u],  endU = rowptr[u + 1];
    int begI = rowptr[it], endI = rowptr[it + 1];
    int nsU = (endU - begU + 7) >> 3;
    int nsI = (endI - begI + 7) >> 3;
    int steps = nsU > nsI ? nsU : nsI;

    float aU[8] = {0.f,0.f,0.f,0.f,0.f,0.f,0.f,0.f};
    float aI[8] = {0.f,0.f,0.f,0.f,0.f,0.f,0.f,0.f};
    for (int s = 0; s < steps; ++s) {
        int iu = begU + 8 * s + g;
        int ii = begI + 8 * s + g;
        int nU = adj[iu];                 // over-read stays inside ws
        int nI = adj[ii];
        nU = (iu < endU) ? nU : NN_;      // masked -> zero row
        nI = (ii < endI) ? nI : NN_;
        half8 au = *(const half8*)(y2 + ((unsigned)nU * 64u + (unsigned)q * 8u));
        half8 ai = *(const half8*)(y2 + ((unsigned)nI * 64u + (unsigned)q * 8u));
#pragma unroll
        for (int k = 0; k < 8; ++k) {
            aU[k] += (float)au[k];
            aI[k] += (float)ai[k];
        }
    }
#pragma unroll
    for (int k = 0; k < 8; ++k) {
        aU[k] += __shfl_xor(aU[k], 8);
        aI[k] += __shfl_xor(aI[k], 8);
        aU[k] += __shfl_xor(aU[k], 16);
        aI[k] += __shfl_xor(aI[k], 16);
        aU[k] += __shfl_xor(aU[k], 32);
        aI[k] += __shfl_xor(aI[k], 32);
    }
    // redistribute: lane wants feature `lane` = 8*(lane>>3) + (lane&7)
    float redU = 0.0f, redI = 0.0f;
#pragma unroll
    for (int k = 0; k < 8; ++k) {
        float tU = __shfl(aU[k], lane >> 3);
        float tI = __shfl(aI[k], lane >> 3);
        if ((lane & 7) == k) { redU = tU; redI = tI; }
    }
    float zu = ue[(size_t)u * D_ + lane]
             + ((float)y1[(unsigned)u * 64u + (unsigned)lane]
              + (float)y2[(unsigned)u * 64u + (unsigned)lane]) * sdeg[u]
             + inv[u] * redU;
    float zi = ie[(size_t)io * D_ + lane]
             + ((float)y1[(unsigned)it * 64u + (unsigned)lane]
              + (float)y2[(unsigned)it * 64u + (unsigned)lane]) * sdeg[it]
             + inv[it] * redI;

    int f = lane >> 4;
    float s = 0.0f;
#pragma unroll
    for (int gg = 0; gg < 4; ++gg) {
        float pi = __shfl(zi, (gg << 4) | (lane & 15));
        float p = zu * pi;
        p += __shfl_xor(p, 1);
        p += __shfl_xor(p, 2);
        p += __shfl_xor(p, 4);
        p += __shfl_xor(p, 8);
        s += fw[f * 4 + gg] * p;
    }
    s += __shfl_xor(s, 16);
    s += __shfl_xor(s, 32);
    if (lane == 0) out[b] = s * 0.0625f;  // (1/4)*(1/4) layer-mean scaling
}

// ---------------------------------------------------------------------------
extern "C" void kernel_launch(void* const* d_in, const int* in_sizes, int n_in,
                              void* d_out, int out_size, void* d_ws, size_t ws_size,
                              hipStream_t stream) {
    const float* ue    = (const float*)d_in[0];  // [NU, 64]
    const float* ie    = (const float*)d_in[1];  // [NI, 64]
    const float* fw    = (const float*)d_in[2];  // [4, 4]
    const int*   eu    = (const int*)d_in[3];    // [E]
    const int*   eitem = (const int*)d_in[4];    // [E]
    const int*   users = (const int*)d_in[5];    // [B]
    const int*   items = (const int*)d_in[6];    // [B]
    float* scores = (float*)d_out;               // [B]

    // (NN+1) rows: row NN is the dedicated zero row for masked gathers.
    const size_t xh_bytes = (size_t)(NN_ + 1) * D_ * 2;       // 89.6 MB + 128 B

    char* ws = (char*)d_ws;
    half8* X0h  = (half8*)ws;  ws += xh_bytes;    // y0 = inv*x0; reused as y2 out
    half8* XAh  = (half8*)ws;  ws += xh_bytes;    // y1
    unsigned int* pairs = (unsigned int*)ws; ws += (size_t)TWO_E * 4;  // 16 MB packed
    int*   adj  = (int*)ws;    ws += (size_t)TWO_E * 4;       // 16 MB
    int*   rowptr = (int*)ws;  ws += (size_t)(NN_ + 1) * 4;
    float* inv  = (float*)ws;  ws += (size_t)NN_ * 4;
    float* sdeg = (float*)ws;  ws += (size_t)NN_ * 4;
    int*   blockHist = (int*)ws; ws += (size_t)NTOT_ * 4;     // 656 KB
    int*   bhScan    = (int*)ws; ws += (size_t)NTOT_ * 4;     // 656 KB
    int*   psum2     = (int*)ws; ws += (size_t)NSCAN2_ * 4;
    int*   poff2     = (int*)ws; ws += (size_t)NSCAN2_ * 4;
    half8* XBh  = X0h;          // ping-pong: X0h dead after pull-1

    // --- radix-style CSR build (no global atomics anywhere) -------------
    hipMemsetAsync((char*)X0h + (size_t)NN_ * 128, 0, 128, stream);
    hipMemsetAsync((char*)XAh + (size_t)NN_ * 128, 0, 128, stream);
    bucket_hist_kernel<<<NB1_, 256, 0, stream>>>(eu, eitem, blockHist, rowptr);
    scan_block<<<NSCAN2_, 1024, 0, stream>>>(blockHist, NTOT_, bhScan, psum2);
    scan_block<<<1, 1024, 0, stream>>>(psum2, NSCAN2_, poff2, (int*)nullptr);
    scan_add_kernel<<<(NTOT_ + 255) / 256, 256, 0, stream>>>(bhScan, poff2, NTOT_);
    bucket_scatter_kernel<<<NB1_, 256, 0, stream>>>(eu, eitem, bhScan, pairs);
    csr_build_kernel<<<NBUCK_, 256, 0, stream>>>(pairs, bhScan, rowptr, adj, inv, sdeg);

    // --- pre-scaled fp16 conversion (after build: needs inv) ------------
    conv_kernel<<<(NN_ * 16) / 256, 256, 0, stream>>>(ue, ie, inv, (half4*)X0h);

    // --- propagation: y1 = inv^2*Sum y0; y2 = inv^2*Sum y1 (unweighted) -
    pull_kernel<<<(NN_ * D_) / 256, 256, 0, stream>>>(X0h, inv, rowptr, adj, XAh);
    pull_kernel<<<(NN_ * D_) / 256, 256, 0, stream>>>(XAh, inv, rowptr, adj, XBh);

    // --- fused finalize (merged dual layer-3 pull) + score --------------
    final_score_kernel<<<(B_ * D_) / 256, 256, 0, stream>>>(
        ue, ie, (const _Float16*)XAh, (const _Float16*)XBh,
        inv, sdeg, rowptr, adj, users, items, fw, scores);
}